// Round 9
// baseline (828.561 us; speedup 1.0000x reference)
//
#include <hip/hip_runtime.h>
#include <hip/hip_bf16.h>
#include <stdint.h>

typedef __bf16 bf16;
typedef __bf16 bf16x8 __attribute__((ext_vector_type(8)));
typedef float floatx4 __attribute__((ext_vector_type(4)));

#define N_NODES 20000
#define MP 20096          // 157*128, padded M
#define HDIM 512
#define KP 1088           // 1029 padded to multiple of 64 (17 BK-iters, 136 chunks)
#define KCH 136
#define FEATD 1029
#define NUM_GAT 5

// ---- async global->LDS, 16B per lane; LDS base must be wave-uniform ----------
typedef __attribute__((address_space(1))) void as1_void;
typedef __attribute__((address_space(3))) void as3_void;
__device__ __forceinline__ void gl_lds16(const void* g, void* l) {
  __builtin_amdgcn_global_load_lds(
      (as1_void*)(uintptr_t)g, (as3_void*)(uintptr_t)l, 16, 0, 0);
}

// ---------------- pack x = concat(feat, goal, info) fp32 -> bf16 [MP][KP] ------
__global__ void pack_kernel(const float* __restrict__ a, const float* __restrict__ goal,
                            const float* __restrict__ info, bf16* __restrict__ xp) {
  int idx = blockIdx.x * 256 + threadIdx.x;
  if (idx >= MP * KCH) return;
  int row = idx / KCH, c = idx % KCH;
  bf16x8 o = {};
  if (row < N_NODES) {
    if (c < 64) {
      const float* p = a + (size_t)row * 512 + c * 8;
      #pragma unroll
      for (int j = 0; j < 8; ++j) o[j] = (bf16)p[j];
    } else if (c < 128) {
      const float* p = goal + (size_t)row * 512 + (c - 64) * 8;
      #pragma unroll
      for (int j = 0; j < 8; ++j) o[j] = (bf16)p[j];
    } else if (c == 128) {
      #pragma unroll
      for (int j = 0; j < 5; ++j) o[j] = (bf16)info[(size_t)row * 5 + j];
    }
  }
  *(bf16x8*)(xp + (size_t)row * KP + c * 8) = o;
}

// ------- LDS-tiled transpose: 8 square 512x512 fp32 -> bf16 [512][512] ---------
struct Ptr8 { const float* p[8]; };
__global__ __launch_bounds__(256) void transpose_sq_kernel(Ptr8 srcs, bf16* __restrict__ dst) {
  __shared__ float tile[64][65];
  int b = blockIdx.x;                  // 8 mats x 64 tiles
  int z = b >> 6, rem = b & 63;
  int kt = rem >> 3, nt = rem & 7;
  int k0 = kt * 64, n0 = nt * 64;
  const float* src = srcs.p[z];
  #pragma unroll
  for (int i = 0; i < 16; ++i) {
    int id = threadIdx.x + i * 256;
    int kk = id >> 6, nn = id & 63;    // consecutive tid -> consecutive nn (coalesced)
    tile[kk][nn] = src[(size_t)(k0 + kk) * 512 + n0 + nn];
  }
  __syncthreads();
  #pragma unroll
  for (int i = 0; i < 16; ++i) {
    int id = threadIdx.x + i * 256;
    int nn = id >> 6, kk = id & 63;    // consecutive tid -> consecutive kk (coalesced)
    dst[(size_t)z * 512 * 512 + (size_t)(n0 + nn) * 512 + k0 + kk] = (bf16)tile[kk][nn];
  }
}

// ------- LDS-tiled transpose: 2 wide 1029x512 fp32 -> bf16 [512][1088], pad ----
struct Ptr2 { const float* p[2]; };
__global__ __launch_bounds__(256) void transpose_wide_kernel(Ptr2 srcs, bf16* __restrict__ dst) {
  __shared__ float tile[64][65];
  int b = blockIdx.x;                  // 2 mats x (17 ktiles x 8 ntiles)
  int z = b / 136, rem = b % 136;
  int kt = rem >> 3, nt = rem & 7;
  int k0 = kt * 64, n0 = nt * 64;
  const float* src = srcs.p[z];
  #pragma unroll
  for (int i = 0; i < 16; ++i) {
    int id = threadIdx.x + i * 256;
    int kk = id >> 6, nn = id & 63;
    int k = k0 + kk;
    tile[kk][nn] = (k < FEATD) ? src[(size_t)k * 512 + n0 + nn] : 0.f;
  }
  __syncthreads();
  #pragma unroll
  for (int i = 0; i < 16; ++i) {
    int id = threadIdx.x + i * 256;
    int nn = id >> 6, kk = id & 63;
    dst[(size_t)z * 512 * KP + (size_t)(n0 + nn) * KP + k0 + kk] = (bf16)tile[kk][nn];
  }
}

// ---------------- CSR build ----------------------------------------------------
__global__ void zero_kernel(int* p, int n) {
  int i = blockIdx.x * 256 + threadIdx.x;
  if (i < n) p[i] = 0;
}
__global__ void hist_kernel(const int* __restrict__ src, int* __restrict__ cnt, int E) {
  int e = blockIdx.x * 256 + threadIdx.x;
  if (e < E) atomicAdd(&cnt[src[e]], 1);
}
__global__ __launch_bounds__(1024) void scan_kernel(int* __restrict__ cnt,
                                                    int* __restrict__ off, int n) {
  __shared__ int wsum[16];
  __shared__ int carry_s;
  int tid = threadIdx.x, lane = tid & 63, w = tid >> 6;
  if (tid == 0) carry_s = 0;
  __syncthreads();
  for (int base = 0; base < n; base += 1024) {
    int i = base + tid;
    int v = (i < n) ? cnt[i] : 0;
    int x = v;  // inclusive wave scan
    #pragma unroll
    for (int o = 1; o < 64; o <<= 1) {
      int y = __shfl_up(x, o);
      if (lane >= o) x += y;
    }
    if (lane == 63) wsum[w] = x;
    __syncthreads();
    int wpre = 0;
    for (int j = 0; j < w; ++j) wpre += wsum[j];
    int incl = x + wpre;
    int c = carry_s;
    if (i < n) { int ex = c + incl - v; off[i] = ex; cnt[i] = ex; }
    __syncthreads();
    if (tid == 1023) carry_s = c + incl;
    __syncthreads();
  }
  if (tid == 0) off[n] = carry_s;
}
__global__ void scatter_kernel(const int* __restrict__ src, const int* __restrict__ dstv,
                               int* __restrict__ cur, int* __restrict__ ssrc,
                               int* __restrict__ sdst, int E) {
  int e = blockIdx.x * 256 + threadIdx.x;
  if (e < E) {
    int sv = src[e];
    int p = atomicAdd(&cur[sv], 1);
    ssrc[p] = sv;
    sdst[p] = dstv[e];
  }
}

// ---------------- bf16 MFMA GEMM: C[M][512] = A[M][K] @ BT[512][K]^T -----------
// 128x128 tile, BK=64, 4 waves (2x2 of 64x64), global_load_lds(16B), XOR-swizzle.
// Optional fused s/t: sv[row] += sum_col C[row,col]*a1[col] (pre-bias, pre-relu).
__global__ __launch_bounds__(256) void gemm_kernel(
    const bf16* __restrict__ A, const bf16* __restrict__ BT, bf16* __restrict__ C,
    int K, const float* __restrict__ bias, int relu,
    float* __restrict__ svp, float* __restrict__ tvp,
    const float* __restrict__ a1g, const float* __restrict__ a2g) {
  __shared__ __align__(16) bf16 sA[128 * 64];
  __shared__ __align__(16) bf16 sB[128 * 64];
  const int tid = threadIdx.x;
  const int lane = tid & 63, wid = tid >> 6;
  const int wr = (wid >> 1) * 64, wc = (wid & 1) * 64;
  const int rowBase = blockIdx.x * 128;
  const int colBase = blockIdx.y * 128;
  const int lrow = lane & 15, lquad = lane >> 4;
  const int xk = lrow & 7;  // read-side XOR key

  floatx4 acc[4][4] = {};

  for (int k0 = 0; k0 < K; k0 += 64) {
    __syncthreads();
    #pragma unroll
    for (int i = 0; i < 4; ++i) {
      int idx = tid + i * 256;            // 0..1023
      int r = idx >> 3, ch = idx & 7;     // row in tile, 16B chunk slot
      int gch = ch ^ (r & 7);             // swizzled global chunk
      gl_lds16(A  + (size_t)(rowBase + r) * K + k0 + gch * 8,
               sA + (size_t)(wid * 64 + i * 256) * 8);
      gl_lds16(BT + (size_t)(colBase + r) * K + k0 + gch * 8,
               sB + (size_t)(wid * 64 + i * 256) * 8);
    }
    __syncthreads();
    #pragma unroll
    for (int kk = 0; kk < 2; ++kk) {
      bf16x8 af[4], bfr[4];
      #pragma unroll
      for (int mi = 0; mi < 4; ++mi)
        af[mi] = *(const bf16x8*)&sA[(wr + mi * 16 + lrow) * 64 +
                                     (((kk * 4 + lquad) ^ xk) * 8)];
      #pragma unroll
      for (int ni = 0; ni < 4; ++ni)
        bfr[ni] = *(const bf16x8*)&sB[(wc + ni * 16 + lrow) * 64 +
                                      (((kk * 4 + lquad) ^ xk) * 8)];
      #pragma unroll
      for (int mi = 0; mi < 4; ++mi)
        #pragma unroll
        for (int ni = 0; ni < 4; ++ni)
          acc[mi][ni] = __builtin_amdgcn_mfma_f32_16x16x32_bf16(af[mi], bfr[ni], acc[mi][ni], 0, 0, 0);
    }
  }

  #pragma unroll
  for (int ni = 0; ni < 4; ++ni) {
    int col = colBase + wc + ni * 16 + lrow;
    float bv = bias ? bias[col] : 0.f;
    #pragma unroll
    for (int mi = 0; mi < 4; ++mi) {
      #pragma unroll
      for (int r = 0; r < 4; ++r) {
        int row = rowBase + wr + mi * 16 + lquad * 4 + r;
        float v = acc[mi][ni][r] + bv;
        if (relu) v = fmaxf(v, 0.f);
        C[(size_t)row * HDIM + col] = (bf16)v;
      }
    }
  }

  // ---- fused s,t = C@a1, C@a2 (GAT layers only) ----
  if (svp) {
    float a1v[4], a2v[4];
    #pragma unroll
    for (int ni = 0; ni < 4; ++ni) {
      int col = colBase + wc + ni * 16 + lrow;
      a1v[ni] = a1g[col];
      a2v[ni] = a2g[col];
    }
    #pragma unroll
    for (int mi = 0; mi < 4; ++mi) {
      #pragma unroll
      for (int r = 0; r < 4; ++r) {
        int row = rowBase + wr + mi * 16 + lquad * 4 + r;
        float ps = 0.f, pt = 0.f;
        #pragma unroll
        for (int ni = 0; ni < 4; ++ni) {
          ps += acc[mi][ni][r] * a1v[ni];
          pt += acc[mi][ni][r] * a2v[ni];
        }
        #pragma unroll
        for (int o = 8; o; o >>= 1) {     // reduce over the 16 lrow lanes
          ps += __shfl_xor(ps, o);
          pt += __shfl_xor(pt, o);
        }
        if (lrow == 0 && row < N_NODES) {
          atomicAdd(&svp[row], ps);
          atomicAdd(&tvp[row], pt);
        }
      }
    }
  }
}

// ------- edge scores: esc[j] = exp(-leakyrelu(s[src]+t[dst])) ------------------
__global__ void edge_score_kernel(const float* __restrict__ s, const float* __restrict__ t,
                                  const int* __restrict__ ssrc, const int* __restrict__ sdst,
                                  float* __restrict__ esc, int E) {
  int j = blockIdx.x * 256 + threadIdx.x;
  if (j >= E) return;
  float sc = s[ssrc[j]] + t[sdst[j]];
  float lr = sc > 0.f ? sc : 0.2f * sc;
  esc[j] = __expf(-lr);
}

// ------- GAT aggregation v3: block per node, 4 waves split edges, LDS combine --
// NOTE: every lane of a wave iterates the SAME edge chunk, so each lane's `den`
// already equals the chunk sum — cross-lane reduction would multiply by 64
// (round-8 bug). Only the cross-wave sum via sden[] is needed.
__global__ __launch_bounds__(256) void agg_kernel(
    const float* __restrict__ esc, const bf16* __restrict__ hp,
    const int* __restrict__ off, const int* __restrict__ sdst,
    bf16* __restrict__ hout, int ostride,
    float* __restrict__ svz, float* __restrict__ tvz) {
  __shared__ float sacc[4][512];
  __shared__ float sden[4];
  const int wid = threadIdx.x >> 6, lane = threadIdx.x & 63;
  const int node = blockIdx.x;
  const int beg = off[node], end = off[node + 1];
  const int cnt = end - beg;
  const int q = (cnt + 3) >> 2;        // per-wave contiguous chunk
  int jb = beg + wid * q;
  int je = jb + q;
  if (jb > end) jb = end;
  if (je > end) je = end;

  float acc[8] = {0.f, 0.f, 0.f, 0.f, 0.f, 0.f, 0.f, 0.f};
  float den = 0.f;
  int j = jb;
  for (; j + 4 <= je; j += 4) {
    int d0 = sdst[j], d1 = sdst[j + 1], d2 = sdst[j + 2], d3 = sdst[j + 3];
    float e0 = esc[j], e1 = esc[j + 1], e2 = esc[j + 2], e3 = esc[j + 3];
    bf16x8 v0 = *(const bf16x8*)(hp + (size_t)d0 * 512 + lane * 8);
    bf16x8 v1 = *(const bf16x8*)(hp + (size_t)d1 * 512 + lane * 8);
    bf16x8 v2 = *(const bf16x8*)(hp + (size_t)d2 * 512 + lane * 8);
    bf16x8 v3 = *(const bf16x8*)(hp + (size_t)d3 * 512 + lane * 8);
    den += (e0 + e1) + (e2 + e3);
    #pragma unroll
    for (int qq = 0; qq < 8; ++qq)
      acc[qq] += e0 * (float)v0[qq] + e1 * (float)v1[qq] +
                 e2 * (float)v2[qq] + e3 * (float)v3[qq];
  }
  for (; j < je; ++j) {
    int d = sdst[j];
    float e = esc[j];
    den += e;
    bf16x8 v = *(const bf16x8*)(hp + (size_t)d * 512 + lane * 8);
    #pragma unroll
    for (int qq = 0; qq < 8; ++qq) acc[qq] += e * (float)v[qq];
  }
  if (lane == 0) sden[wid] = den;   // den identical across lanes: NO cross-lane reduce
  #pragma unroll
  for (int qq = 0; qq < 8; ++qq) sacc[wid][lane * 8 + qq] = acc[qq];
  __syncthreads();
  if (wid == 0) {
    if (lane == 0) { svz[node] = 0.f; tvz[node] = 0.f; }
    float inv = 1.f / (sden[0] + sden[1] + sden[2] + sden[3] + 1e-10f);
    bf16x8 o;
    #pragma unroll
    for (int qq = 0; qq < 8; ++qq) {
      int c = lane * 8 + qq;
      float v = sacc[0][c] + sacc[1][c] + sacc[2][c] + sacc[3][c];
      o[qq] = (bf16)fmaxf(v * inv, 0.f);   // relu
    }
    *(bf16x8*)(hout + (size_t)node * ostride + lane * 8) = o;
  }
}

// -------- final: out = sigmoid(t2 @ V3 + vb3), V3/vb3 fp32, out fp32 -----------
__global__ void final_kernel(const bf16* __restrict__ t2, const float* __restrict__ V3,
                             const float* __restrict__ vb3, float* __restrict__ out) {
  int gid = blockIdx.x * 256 + threadIdx.x;
  int node = gid >> 6, lane = gid & 63;
  if (node >= N_NODES) return;
  bf16x8 hv = *(const bf16x8*)(t2 + (size_t)node * 512 + lane * 8);
  float p = 0.f;
  #pragma unroll
  for (int q = 0; q < 8; ++q) p += (float)hv[q] * V3[lane * 8 + q];
  #pragma unroll
  for (int o = 32; o > 0; o >>= 1) p += __shfl_xor(p, o);
  if (lane == 0) {
    float z = p + vb3[0];
    out[node] = 1.f / (1.f + __expf(-z));
  }
}

// ------------------------------------------------------------------------------
extern "C" void kernel_launch(void* const* d_in, const int* in_sizes, int n_in,
                              void* d_out, int out_size, void* d_ws, size_t ws_size,
                              hipStream_t stream) {
  const float* feat = (const float*)d_in[0];
  const float* goal = (const float*)d_in[1];
  const float* info = (const float*)d_in[2];
  const int* esrc   = (const int*)d_in[3];
  const int* edst   = (const int*)d_in[4];
  const float* W1  = (const float*)d_in[5];
  const float* b1  = (const float*)d_in[6];
  const float* W2  = (const float*)d_in[7];
  const float* b2  = (const float*)d_in[8];
  const float* W3  = (const float*)d_in[9];
  const float* b3  = (const float*)d_in[10];
  const float* V1  = (const float*)d_in[11];
  const float* vb1 = (const float*)d_in[12];
  const float* V2  = (const float*)d_in[13];
  const float* vb2 = (const float*)d_in[14];
  const float* V3  = (const float*)d_in[15];
  const float* vb3 = (const float*)d_in[16];
  const float* gatW = (const float*)d_in[17];
  const float* gatA = (const float*)d_in[18];
  float* out = (float*)d_out;
  const int E = in_sizes[3];
  const size_t SQ = 512 * 512;

  // ---- carve workspace
  char* w = (char*)d_ws;
  auto alloc = [&](size_t bytes) {
    char* p = w;
    w += (bytes + 255) & ~(size_t)255;
    return p;
  };
  bf16* xpad = (bf16*)alloc((size_t)MP * KP * 2);
  bf16* wkt  = (bf16*)alloc((size_t)2 * 512 * KP * 2);   // [0]=W1T, [1]=V1T
  bf16* wsq  = (bf16*)alloc((size_t)8 * SQ * 2);         // W2,W3,V2,gatW[0..4]
  bf16* hA   = (bf16*)alloc((size_t)MP * 512 * 2);
  bf16* hB   = (bf16*)alloc((size_t)MP * 512 * 2);
  bf16* hp   = (bf16*)alloc((size_t)MP * 512 * 2);
  float* stv = (float*)alloc((size_t)2 * N_NODES * 4);   // sv | tv contiguous
  int* off   = (int*)alloc((size_t)(N_NODES + 1) * 4);
  int* cur   = (int*)alloc((size_t)(N_NODES + 1) * 4);
  int* ssrc  = (int*)alloc((size_t)E * 4);
  int* sdst  = (int*)alloc((size_t)E * 4);
  float* esc = (float*)alloc((size_t)E * 4);

  bf16* w1t = wkt;
  bf16* v1t = wkt + (size_t)512 * KP;
  bf16* w2t = wsq;
  bf16* w3t = wsq + SQ;
  bf16* v2t = wsq + 2 * SQ;
  bf16* gwt = wsq + 3 * SQ;
  float* sv = stv;
  float* tv = stv + N_NODES;

  const int eb = (E + 255) / 256;

  // ---- pack x, transpose+convert weights (LDS-tiled)
  pack_kernel<<<(MP * KCH + 255) / 256, 256, 0, stream>>>(feat, goal, info, xpad);
  Ptr2 wide; wide.p[0] = W1; wide.p[1] = V1;
  transpose_wide_kernel<<<2 * 136, 256, 0, stream>>>(wide, wkt);
  Ptr8 sq;
  sq.p[0] = W2; sq.p[1] = W3; sq.p[2] = V2;
  for (int i = 0; i < NUM_GAT; ++i) sq.p[3 + i] = gatW + (size_t)i * SQ;
  transpose_sq_kernel<<<8 * 64, 256, 0, stream>>>(sq, wsq);

  // ---- CSR build (sorted-by-src gather lists)
  zero_kernel<<<(N_NODES + 255) / 256, 256, 0, stream>>>(cur, N_NODES);
  hist_kernel<<<eb, 256, 0, stream>>>(esrc, cur, E);
  scan_kernel<<<1, 1024, 0, stream>>>(cur, off, N_NODES);
  scatter_kernel<<<eb, 256, 0, stream>>>(esrc, edst, cur, ssrc, sdst, E);

  // ---- zero sv/tv for the first fused-st GEMM
  zero_kernel<<<(2 * N_NODES + 255) / 256, 256, 0, stream>>>((int*)stv, 2 * N_NODES);

  dim3 gg(MP / 128, HDIM / 128), gb(256);
  // ---- input MLP3
  gemm_kernel<<<gg, gb, 0, stream>>>(xpad, w1t, hA, KP, b1, 1,
                                     nullptr, nullptr, nullptr, nullptr);
  gemm_kernel<<<gg, gb, 0, stream>>>(hA, w2t, hB, 512, b2, 1,
                                     nullptr, nullptr, nullptr, nullptr);
  gemm_kernel<<<gg, gb, 0, stream>>>(hB, w3t, hA, 512, b3, 0,
                                     nullptr, nullptr, nullptr, nullptr);

  // ---- GAT layers (gemm computes hp AND s,t; agg re-zeroes sv/tv per node)
  bf16* ha = hA;
  bf16* hb = hB;
  for (int i = 0; i < NUM_GAT; ++i) {
    gemm_kernel<<<gg, gb, 0, stream>>>(ha, gwt + (size_t)i * SQ, hp, 512,
                                       nullptr, 0, sv, tv,
                                       gatA + (size_t)i * 1024,
                                       gatA + (size_t)i * 1024 + 512);
    edge_score_kernel<<<eb, 256, 0, stream>>>(sv, tv, ssrc, sdst, esc, E);
    if (i == NUM_GAT - 1) {
      agg_kernel<<<N_NODES, 256, 0, stream>>>(esc, hp, off, sdst, xpad, KP, sv, tv);
    } else {
      agg_kernel<<<N_NODES, 256, 0, stream>>>(esc, hp, off, sdst, hb, 512, sv, tv);
      bf16* tmp = ha; ha = hb; hb = tmp;
    }
  }

  // ---- output MLP3 + sigmoid (xpad already holds [h, goal, info])
  gemm_kernel<<<gg, gb, 0, stream>>>(xpad, v1t, hB, KP, vb1, 1,
                                     nullptr, nullptr, nullptr, nullptr);
  gemm_kernel<<<gg, gb, 0, stream>>>(hB, v2t, hp, 512, vb2, 1,
                                     nullptr, nullptr, nullptr, nullptr);
  final_kernel<<<(N_NODES * 64 + 255) / 256, 256, 0, stream>>>(hp, V3, vb3, out);
}

// Round 10
// 706.098 us; speedup vs baseline: 1.1734x; 1.1734x over previous
//
#include <hip/hip_runtime.h>
#include <hip/hip_bf16.h>
#include <stdint.h>

typedef __bf16 bf16;
typedef __bf16 bf16x8 __attribute__((ext_vector_type(8)));
typedef float floatx4 __attribute__((ext_vector_type(4)));

#define N_NODES 20000
#define MP 20096          // 157*128, padded M
#define HDIM 512
#define KP 1088           // 1029 padded to multiple of 64 (17 BK-iters, 136 chunks)
#define KCH 136
#define FEATD 1029
#define NUM_GAT 5
#define ROWT (MP / 128)   // 157 row tiles

// ---- async global->LDS, 16B per lane; LDS base must be wave-uniform ----------
typedef __attribute__((address_space(1))) void as1_void;
typedef __attribute__((address_space(3))) void as3_void;
__device__ __forceinline__ void gl_lds16(const void* g, void* l) {
  __builtin_amdgcn_global_load_lds(
      (as1_void*)(uintptr_t)g, (as3_void*)(uintptr_t)l, 16, 0, 0);
}

// ---------------- pack x = concat(feat, goal, info) fp32 -> bf16 [MP][KP] ------
__global__ void pack_kernel(const float* __restrict__ a, const float* __restrict__ goal,
                            const float* __restrict__ info, bf16* __restrict__ xp) {
  int idx = blockIdx.x * 256 + threadIdx.x;
  if (idx >= MP * KCH) return;
  int row = idx / KCH, c = idx % KCH;
  bf16x8 o = {};
  if (row < N_NODES) {
    if (c < 64) {
      const float* p = a + (size_t)row * 512 + c * 8;
      #pragma unroll
      for (int j = 0; j < 8; ++j) o[j] = (bf16)p[j];
    } else if (c < 128) {
      const float* p = goal + (size_t)row * 512 + (c - 64) * 8;
      #pragma unroll
      for (int j = 0; j < 8; ++j) o[j] = (bf16)p[j];
    } else if (c == 128) {
      #pragma unroll
      for (int j = 0; j < 5; ++j) o[j] = (bf16)info[(size_t)row * 5 + j];
    }
  }
  *(bf16x8*)(xp + (size_t)row * KP + c * 8) = o;
}

// ------- LDS-tiled transpose: 8 square 512x512 fp32 -> bf16 [512][512] ---------
struct Ptr8 { const float* p[8]; };
__global__ __launch_bounds__(256) void transpose_sq_kernel(Ptr8 srcs, bf16* __restrict__ dst) {
  __shared__ float tile[64][65];
  int b = blockIdx.x;                  // 8 mats x 64 tiles
  int z = b >> 6, rem = b & 63;
  int kt = rem >> 3, nt = rem & 7;
  int k0 = kt * 64, n0 = nt * 64;
  const float* src = srcs.p[z];
  #pragma unroll
  for (int i = 0; i < 16; ++i) {
    int id = threadIdx.x + i * 256;
    int kk = id >> 6, nn = id & 63;
    tile[kk][nn] = src[(size_t)(k0 + kk) * 512 + n0 + nn];
  }
  __syncthreads();
  #pragma unroll
  for (int i = 0; i < 16; ++i) {
    int id = threadIdx.x + i * 256;
    int nn = id >> 6, kk = id & 63;
    dst[(size_t)z * 512 * 512 + (size_t)(n0 + nn) * 512 + k0 + kk] = (bf16)tile[kk][nn];
  }
}

// ------- LDS-tiled transpose: 2 wide 1029x512 fp32 -> bf16 [512][1088], pad ----
struct Ptr2 { const float* p[2]; };
__global__ __launch_bounds__(256) void transpose_wide_kernel(Ptr2 srcs, bf16* __restrict__ dst) {
  __shared__ float tile[64][65];
  int b = blockIdx.x;                  // 2 mats x (17 ktiles x 8 ntiles)
  int z = b / 136, rem = b % 136;
  int kt = rem >> 3, nt = rem & 7;
  int k0 = kt * 64, n0 = nt * 64;
  const float* src = srcs.p[z];
  #pragma unroll
  for (int i = 0; i < 16; ++i) {
    int id = threadIdx.x + i * 256;
    int kk = id >> 6, nn = id & 63;
    int k = k0 + kk;
    tile[kk][nn] = (k < FEATD) ? src[(size_t)k * 512 + n0 + nn] : 0.f;
  }
  __syncthreads();
  #pragma unroll
  for (int i = 0; i < 16; ++i) {
    int id = threadIdx.x + i * 256;
    int nn = id >> 6, kk = id & 63;
    dst[(size_t)z * 512 * KP + (size_t)(n0 + nn) * KP + k0 + kk] = (bf16)tile[kk][nn];
  }
}

// ---------------- CSR build ----------------------------------------------------
__global__ void zero_kernel(int* p, int n) {
  int i = blockIdx.x * 256 + threadIdx.x;
  if (i < n) p[i] = 0;
}
__global__ void hist_kernel(const int* __restrict__ src, int* __restrict__ cnt, int E) {
  int e = blockIdx.x * 256 + threadIdx.x;
  if (e < E) atomicAdd(&cnt[src[e]], 1);
}
__global__ __launch_bounds__(1024) void scan_kernel(int* __restrict__ cnt,
                                                    int* __restrict__ off, int n) {
  __shared__ int wsum[16];
  __shared__ int carry_s;
  int tid = threadIdx.x, lane = tid & 63, w = tid >> 6;
  if (tid == 0) carry_s = 0;
  __syncthreads();
  for (int base = 0; base < n; base += 1024) {
    int i = base + tid;
    int v = (i < n) ? cnt[i] : 0;
    int x = v;  // inclusive wave scan
    #pragma unroll
    for (int o = 1; o < 64; o <<= 1) {
      int y = __shfl_up(x, o);
      if (lane >= o) x += y;
    }
    if (lane == 63) wsum[w] = x;
    __syncthreads();
    int wpre = 0;
    for (int j = 0; j < w; ++j) wpre += wsum[j];
    int incl = x + wpre;
    int c = carry_s;
    if (i < n) { int ex = c + incl - v; off[i] = ex; cnt[i] = ex; }
    __syncthreads();
    if (tid == 1023) carry_s = c + incl;
    __syncthreads();
  }
  if (tid == 0) off[n] = carry_s;
}
__global__ void scatter_kernel(const int* __restrict__ src, const int* __restrict__ dstv,
                               int* __restrict__ cur, int* __restrict__ sdst, int E) {
  int e = blockIdx.x * 256 + threadIdx.x;
  if (e < E) {
    int p = atomicAdd(&cur[src[e]], 1);
    sdst[p] = dstv[e];
  }
}

// ---------------- bf16 MFMA GEMM: C[M][512] = A[M][K] @ BT[512][K]^T -----------
// 128x128 tile, BK=64, double-buffered global_load_lds with manual
// s_waitcnt vmcnt(8) + raw s_barrier so the next tile's loads stay in flight
// across the barrier (AITER-style). XOR-swizzled LDS chunks (conflict-free
// ds_read_b128, verified SQ_LDS_BANK_CONFLICT=0). Flat 640-block grid with
// XCD swizzle: the 4 column tiles of one A row-strip are 8 apart in dispatch
// order -> same XCD under round-robin -> A fetched from HBM ~once.
__global__ __launch_bounds__(256) void gemm_kernel(
    const bf16* __restrict__ A, const bf16* __restrict__ BT, bf16* __restrict__ C,
    int K, const float* __restrict__ bias, int relu) {
  __shared__ __align__(16) bf16 sA[2][128 * 64];
  __shared__ __align__(16) bf16 sB[2][128 * 64];
  const int flat = blockIdx.x;
  const int rowT = ((flat >> 5) << 3) | (flat & 7);
  const int colT = (flat >> 3) & 3;
  if (rowT >= ROWT) return;
  const int tid = threadIdx.x;
  const int lane = tid & 63, wid = tid >> 6;
  const int wr = (wid >> 1) * 64, wc = (wid & 1) * 64;
  const int rowBase = rowT * 128;
  const int colBase = colT * 128;
  const int lrow = lane & 15, lquad = lane >> 4;
  const int xk = lrow & 7;  // read-side XOR key

  floatx4 acc[4][4] = {};
  const int nk = K >> 6;

  auto stage = [&](int buf, int k0) {
    #pragma unroll
    for (int i = 0; i < 4; ++i) {
      int idx = tid + i * 256;            // 0..1023
      int rr = idx >> 3, cc = idx & 7;    // row in tile, 16B chunk slot
      int gch = cc ^ (rr & 7);            // swizzled global chunk
      gl_lds16(A  + (size_t)(rowBase + rr) * K + k0 + gch * 8,
               &sA[buf][(size_t)(wid * 64 + i * 256) * 8]);
      gl_lds16(BT + (size_t)(colBase + rr) * K + k0 + gch * 8,
               &sB[buf][(size_t)(wid * 64 + i * 256) * 8]);
    }
  };

  stage(0, 0);
  for (int kt = 0; kt < nk; ++kt) {
    const int cur = kt & 1;
    if (kt + 1 < nk) {
      stage(cur ^ 1, (kt + 1) << 6);
      // vmcnt(8): wait for current buffer's 8 loads; prefetch stays in flight.
      __builtin_amdgcn_s_waitcnt(0xF78);
    } else {
      __builtin_amdgcn_s_waitcnt(0xF70);  // vmcnt(0)
    }
    __builtin_amdgcn_s_barrier();
    #pragma unroll
    for (int kk = 0; kk < 2; ++kk) {
      bf16x8 af[4], bfr[4];
      #pragma unroll
      for (int mi = 0; mi < 4; ++mi)
        af[mi] = *(const bf16x8*)&sA[cur][(wr + mi * 16 + lrow) * 64 +
                                         (((kk * 4 + lquad) ^ xk) * 8)];
      #pragma unroll
      for (int ni = 0; ni < 4; ++ni)
        bfr[ni] = *(const bf16x8*)&sB[cur][(wc + ni * 16 + lrow) * 64 +
                                          (((kk * 4 + lquad) ^ xk) * 8)];
      #pragma unroll
      for (int mi = 0; mi < 4; ++mi)
        #pragma unroll
        for (int ni = 0; ni < 4; ++ni)
          acc[mi][ni] = __builtin_amdgcn_mfma_f32_16x16x32_bf16(af[mi], bfr[ni], acc[mi][ni], 0, 0, 0);
    }
    // ds_reads are complete (consumed by MFMA) before this barrier; the next
    // stage() may then safely overwrite the buffer other waves just read.
    __builtin_amdgcn_s_barrier();
  }

  #pragma unroll
  for (int ni = 0; ni < 4; ++ni) {
    int col = colBase + wc + ni * 16 + lrow;
    float bv = bias ? bias[col] : 0.f;
    #pragma unroll
    for (int mi = 0; mi < 4; ++mi) {
      #pragma unroll
      for (int r = 0; r < 4; ++r) {
        int row = rowBase + wr + mi * 16 + lquad * 4 + r;
        float v = acc[mi][ni][r] + bv;
        if (relu) v = fmaxf(v, 0.f);
        C[(size_t)row * HDIM + col] = (bf16)v;
      }
    }
  }
}

// ---------------- s = h'@a1, t = h'@a2 (wave per node; a fp32) -----------------
__global__ void st_kernel(const bf16* __restrict__ hp, const float* __restrict__ a1,
                          const float* __restrict__ a2, float* __restrict__ s,
                          float* __restrict__ t) {
  int gid = blockIdx.x * 256 + threadIdx.x;
  int node = gid >> 6, lane = gid & 63;
  if (node >= N_NODES) return;
  bf16x8 hv = *(const bf16x8*)(hp + (size_t)node * 512 + lane * 8);
  float ps = 0.f, pt = 0.f;
  #pragma unroll
  for (int q = 0; q < 8; ++q) {
    float h = (float)hv[q];
    ps += h * a1[lane * 8 + q];
    pt += h * a2[lane * 8 + q];
  }
  #pragma unroll
  for (int o = 32; o > 0; o >>= 1) {
    ps += __shfl_xor(ps, o);
    pt += __shfl_xor(pt, o);
  }
  if (lane == 0) { s[node] = ps; t[node] = pt; }
}

// ------- GAT aggregation v3: block per node, 4 waves split edges, LDS combine --
// Edge score computed inline: e = exp(-leakyrelu(s[node]+t[d])). All lanes of a
// wave iterate the SAME edge chunk, so per-lane den already equals the chunk
// sum — only the cross-wave sum via sden[] is needed (round-8 lesson).
__global__ __launch_bounds__(256) void agg_kernel(
    const float* __restrict__ s, const float* __restrict__ t,
    const bf16* __restrict__ hp, const int* __restrict__ off,
    const int* __restrict__ sdst, bf16* __restrict__ hout, int ostride) {
  __shared__ float sacc[4][512];
  __shared__ float sden[4];
  const int wid = threadIdx.x >> 6, lane = threadIdx.x & 63;
  const int node = blockIdx.x;
  const int beg = off[node], end = off[node + 1];
  const int cnt = end - beg;
  const int q = (cnt + 3) >> 2;        // per-wave contiguous chunk
  int jb = beg + wid * q;
  int je = jb + q;
  if (jb > end) jb = end;
  if (je > end) je = end;
  const float si = s[node];

  float acc[8] = {0.f, 0.f, 0.f, 0.f, 0.f, 0.f, 0.f, 0.f};
  float den = 0.f;
  int j = jb;
  for (; j + 4 <= je; j += 4) {
    int d0 = sdst[j], d1 = sdst[j + 1], d2 = sdst[j + 2], d3 = sdst[j + 3];
    float t0 = t[d0], t1 = t[d1], t2 = t[d2], t3 = t[d3];
    bf16x8 v0 = *(const bf16x8*)(hp + (size_t)d0 * 512 + lane * 8);
    bf16x8 v1 = *(const bf16x8*)(hp + (size_t)d1 * 512 + lane * 8);
    bf16x8 v2 = *(const bf16x8*)(hp + (size_t)d2 * 512 + lane * 8);
    bf16x8 v3 = *(const bf16x8*)(hp + (size_t)d3 * 512 + lane * 8);
    float s0 = si + t0, s1 = si + t1, s2 = si + t2, s3 = si + t3;
    float l0 = s0 > 0.f ? s0 : 0.2f * s0;
    float l1 = s1 > 0.f ? s1 : 0.2f * s1;
    float l2 = s2 > 0.f ? s2 : 0.2f * s2;
    float l3 = s3 > 0.f ? s3 : 0.2f * s3;
    float e0 = __expf(-l0), e1 = __expf(-l1), e2 = __expf(-l2), e3 = __expf(-l3);
    den += (e0 + e1) + (e2 + e3);
    #pragma unroll
    for (int qq = 0; qq < 8; ++qq)
      acc[qq] += e0 * (float)v0[qq] + e1 * (float)v1[qq] +
                 e2 * (float)v2[qq] + e3 * (float)v3[qq];
  }
  for (; j < je; ++j) {
    int d = sdst[j];
    float sc = si + t[d];
    float lr = sc > 0.f ? sc : 0.2f * sc;
    float e = __expf(-lr);
    den += e;
    bf16x8 v = *(const bf16x8*)(hp + (size_t)d * 512 + lane * 8);
    #pragma unroll
    for (int qq = 0; qq < 8; ++qq) acc[qq] += e * (float)v[qq];
  }
  if (lane == 0) sden[wid] = den;   // den identical across lanes: NO cross-lane reduce
  #pragma unroll
  for (int qq = 0; qq < 8; ++qq) sacc[wid][lane * 8 + qq] = acc[qq];
  __syncthreads();
  if (wid == 0) {
    float inv = 1.f / (sden[0] + sden[1] + sden[2] + sden[3] + 1e-10f);
    bf16x8 o;
    #pragma unroll
    for (int qq = 0; qq < 8; ++qq) {
      int c = lane * 8 + qq;
      float v = sacc[0][c] + sacc[1][c] + sacc[2][c] + sacc[3][c];
      o[qq] = (bf16)fmaxf(v * inv, 0.f);   // relu
    }
    *(bf16x8*)(hout + (size_t)node * ostride + lane * 8) = o;
  }
}

// -------- final: out = sigmoid(t2 @ V3 + vb3), V3/vb3 fp32, out fp32 -----------
__global__ void final_kernel(const bf16* __restrict__ t2, const float* __restrict__ V3,
                             const float* __restrict__ vb3, float* __restrict__ out) {
  int gid = blockIdx.x * 256 + threadIdx.x;
  int node = gid >> 6, lane = gid & 63;
  if (node >= N_NODES) return;
  bf16x8 hv = *(const bf16x8*)(t2 + (size_t)node * 512 + lane * 8);
  float p = 0.f;
  #pragma unroll
  for (int q = 0; q < 8; ++q) p += (float)hv[q] * V3[lane * 8 + q];
  #pragma unroll
  for (int o = 32; o > 0; o >>= 1) p += __shfl_xor(p, o);
  if (lane == 0) {
    float z = p + vb3[0];
    out[node] = 1.f / (1.f + __expf(-z));
  }
}

// ------------------------------------------------------------------------------
extern "C" void kernel_launch(void* const* d_in, const int* in_sizes, int n_in,
                              void* d_out, int out_size, void* d_ws, size_t ws_size,
                              hipStream_t stream) {
  const float* feat = (const float*)d_in[0];
  const float* goal = (const float*)d_in[1];
  const float* info = (const float*)d_in[2];
  const int* esrc   = (const int*)d_in[3];
  const int* edst   = (const int*)d_in[4];
  const float* W1  = (const float*)d_in[5];
  const float* b1  = (const float*)d_in[6];
  const float* W2  = (const float*)d_in[7];
  const float* b2  = (const float*)d_in[8];
  const float* W3  = (const float*)d_in[9];
  const float* b3  = (const float*)d_in[10];
  const float* V1  = (const float*)d_in[11];
  const float* vb1 = (const float*)d_in[12];
  const float* V2  = (const float*)d_in[13];
  const float* vb2 = (const float*)d_in[14];
  const float* V3  = (const float*)d_in[15];
  const float* vb3 = (const float*)d_in[16];
  const float* gatW = (const float*)d_in[17];
  const float* gatA = (const float*)d_in[18];
  float* out = (float*)d_out;
  const int E = in_sizes[3];
  const size_t SQ = 512 * 512;

  // ---- carve workspace
  char* w = (char*)d_ws;
  auto alloc = [&](size_t bytes) {
    char* p = w;
    w += (bytes + 255) & ~(size_t)255;
    return p;
  };
  bf16* xpad = (bf16*)alloc((size_t)MP * KP * 2);
  bf16* wkt  = (bf16*)alloc((size_t)2 * 512 * KP * 2);   // [0]=W1T, [1]=V1T
  bf16* wsq  = (bf16*)alloc((size_t)8 * SQ * 2);         // W2,W3,V2,gatW[0..4]
  bf16* hA   = (bf16*)alloc((size_t)MP * 512 * 2);
  bf16* hB   = (bf16*)alloc((size_t)MP * 512 * 2);
  bf16* hp   = (bf16*)alloc((size_t)MP * 512 * 2);
  float* sv  = (float*)alloc((size_t)N_NODES * 4);
  float* tv  = (float*)alloc((size_t)N_NODES * 4);
  int* off   = (int*)alloc((size_t)(N_NODES + 1) * 4);
  int* cur   = (int*)alloc((size_t)(N_NODES + 1) * 4);
  int* sdst  = (int*)alloc((size_t)E * 4);

  bf16* w1t = wkt;
  bf16* v1t = wkt + (size_t)512 * KP;
  bf16* w2t = wsq;
  bf16* w3t = wsq + SQ;
  bf16* v2t = wsq + 2 * SQ;
  bf16* gwt = wsq + 3 * SQ;

  const int eb = (E + 255) / 256;

  // ---- pack x, transpose+convert weights (LDS-tiled)
  pack_kernel<<<(MP * KCH + 255) / 256, 256, 0, stream>>>(feat, goal, info, xpad);
  Ptr2 wide; wide.p[0] = W1; wide.p[1] = V1;
  transpose_wide_kernel<<<2 * 136, 256, 0, stream>>>(wide, wkt);
  Ptr8 sq;
  sq.p[0] = W2; sq.p[1] = W3; sq.p[2] = V2;
  for (int i = 0; i < NUM_GAT; ++i) sq.p[3 + i] = gatW + (size_t)i * SQ;
  transpose_sq_kernel<<<8 * 64, 256, 0, stream>>>(sq, wsq);

  // ---- CSR build (sorted-by-src gather lists)
  zero_kernel<<<(N_NODES + 255) / 256, 256, 0, stream>>>(cur, N_NODES);
  hist_kernel<<<eb, 256, 0, stream>>>(esrc, cur, E);
  scan_kernel<<<1, 1024, 0, stream>>>(cur, off, N_NODES);
  scatter_kernel<<<eb, 256, 0, stream>>>(esrc, edst, cur, sdst, E);

  const int gg = 640;  // XCD-swizzled flat grid (160 row tiles x 4 col tiles)
  // ---- input MLP3
  gemm_kernel<<<gg, 256, 0, stream>>>(xpad, w1t, hA, KP, b1, 1);
  gemm_kernel<<<gg, 256, 0, stream>>>(hA, w2t, hB, 512, b2, 1);
  gemm_kernel<<<gg, 256, 0, stream>>>(hB, w3t, hA, 512, b3, 0);

  // ---- GAT layers (layer 4 writes straight into xpad cols 0..511)
  bf16* ha = hA;
  bf16* hb = hB;
  for (int i = 0; i < NUM_GAT; ++i) {
    gemm_kernel<<<gg, 256, 0, stream>>>(ha, gwt + (size_t)i * SQ, hp, 512,
                                        (const float*)nullptr, 0);
    st_kernel<<<(N_NODES * 64 + 255) / 256, 256, 0, stream>>>(
        hp, gatA + (size_t)i * 1024, gatA + (size_t)i * 1024 + 512, sv, tv);
    if (i == NUM_GAT - 1) {
      agg_kernel<<<N_NODES, 256, 0, stream>>>(sv, tv, hp, off, sdst, xpad, KP);
    } else {
      agg_kernel<<<N_NODES, 256, 0, stream>>>(sv, tv, hp, off, sdst, hb, 512);
      bf16* tmp = ha; ha = hb; hb = tmp;
    }
  }

  // ---- output MLP3 + sigmoid (xpad already holds [h, goal, info])
  gemm_kernel<<<gg, 256, 0, stream>>>(xpad, v1t, hB, KP, vb1, 1);
  gemm_kernel<<<gg, 256, 0, stream>>>(hB, v2t, hp, 512, vb2, 1);
  final_kernel<<<(N_NODES * 64 + 255) / 256, 256, 0, stream>>>(hp, V3, vb3, out);
}